// Round 2
// baseline (3062.030 us; speedup 1.0000x reference)
//
#include <hip/hip_runtime.h>

#define T_STEPS 20
#define B_SIZE  1024
#define D_SIZE  2312
#define BLOCK   256
#define NPT     10   // ceil(2312/256)
#define GRID    B_SIZE

// Workspace layout (floats): acc[t] at ws_f[32*t] (t<20, 128B apart),
// barrier count at ws_f[704], barrier gen at ws_f[736]. 768 words zeroed.
#define WS_WORDS   768
#define ACC_STRIDE 32
#define CNT_OFF    704
#define GEN_OFF    736

__device__ __forceinline__ float sigmoidf_(float x) {
    return 1.0f / (1.0f + __expf(-x));
}

__device__ __forceinline__ float blockReduceMax(float v, float* s) {
    #pragma unroll
    for (int o = 32; o > 0; o >>= 1) v = fmaxf(v, __shfl_down(v, o, 64));
    const int wid = threadIdx.x >> 6;
    if ((threadIdx.x & 63) == 0) s[wid] = v;
    __syncthreads();
    float r = fmaxf(fmaxf(s[0], s[1]), fmaxf(s[2], s[3]));
    __syncthreads();
    return r;
}

__device__ __forceinline__ float blockReduceSum(float v, float* s) {
    #pragma unroll
    for (int o = 32; o > 0; o >>= 1) v += __shfl_down(v, o, 64);
    const int wid = threadIdx.x >> 6;
    if ((threadIdx.x & 63) == 0) s[wid] = v;
    __syncthreads();
    float r = (s[0] + s[1]) + (s[2] + s[3]);
    __syncthreads();
    return r;
}

__device__ __forceinline__ void blockReduceSum2(float& a, float& b, float* sa, float* sb) {
    #pragma unroll
    for (int o = 32; o > 0; o >>= 1) {
        a += __shfl_down(a, o, 64);
        b += __shfl_down(b, o, 64);
    }
    const int wid = threadIdx.x >> 6;
    if ((threadIdx.x & 63) == 0) { sa[wid] = a; sb[wid] = b; }
    __syncthreads();
    a = (sa[0] + sa[1]) + (sa[2] + sa[3]);
    b = (sb[0] + sb[1]) + (sb[2] + sb[3]);
    __syncthreads();
}

__global__ void zero_ws_kernel(float* ws) {
    for (int i = threadIdx.x; i < WS_WORDS; i += BLOCK) ws[i] = 0.0f;
}

// Manual grid barrier: all GRID blocks must be co-resident.
// launch_bounds(256,4) caps VGPR at 128 -> HW capacity = 4 blocks/CU x 256 CU
// = 1024 = GRID, so residency holds. Bounded spin turns any surprise into a
// wrong-answer failure instead of a harness hang.
__device__ __forceinline__ void grid_barrier(int* cnt, int* gen, int t) {
    __syncthreads();
    if (threadIdx.x == 0) {
        __threadfence();
        int old = __hip_atomic_fetch_add(cnt, 1, __ATOMIC_ACQ_REL,
                                         __HIP_MEMORY_SCOPE_AGENT);
        if (old == GRID - 1) {
            __hip_atomic_store(cnt, 0, __ATOMIC_RELAXED, __HIP_MEMORY_SCOPE_AGENT);
            __hip_atomic_store(gen, t + 1, __ATOMIC_RELEASE, __HIP_MEMORY_SCOPE_AGENT);
        } else {
            int spins = 0;
            while (__hip_atomic_load(gen, __ATOMIC_ACQUIRE,
                                     __HIP_MEMORY_SCOPE_AGENT) < t + 1) {
                __builtin_amdgcn_s_sleep(8);
                if (++spins > (1 << 22)) break;   // ~1s failsafe
            }
        }
        __threadfence();
    }
    __syncthreads();
}

__global__ void __launch_bounds__(BLOCK, 4)
snn_atic_lif(const float* __restrict__ x,  const float* __restrict__ ac,
             const float* __restrict__ tw, const float* __restrict__ ig,
             const float* __restrict__ mdp, const float* __restrict__ sdp,
             const float* __restrict__ thp, float* __restrict__ out,
             float* __restrict__ ws)
{
    __shared__ float sA[4];
    __shared__ float sB[4];

    int* cnt = (int*)&ws[CNT_OFF];
    int* gen = (int*)&ws[GEN_OFF];

    const int b   = blockIdx.x;   // one block per batch row
    const int tid = threadIdx.x;
    const float md = mdp[0];
    const float sd = sdp[0];
    const float th = thp[0];
    const float invBD = 1.0f / ((float)B_SIZE * (float)D_SIZE);

    // Persistent per-thread state: element d = tid + k*BLOCK of row b.
    float acg[NPT], gg[NPT], iS[NPT], vS[NPT], xa[NPT], ca[NPT];

    #pragma unroll
    for (int k = 0; k < NPT; ++k) {
        const int d = tid + k * BLOCK;
        const bool ok = (d < D_SIZE);
        const float a  = ok ? ac[d] : 0.0f;
        const float t1 = ok ? tw[d] : 0.0f;
        const float t2 = ok ? ig[d] : 0.0f;
        acg[k] = a;
        gg[k]  = ok ? (sigmoidf_(t1) * sigmoidf_(t2)) : 0.0f;
        iS[k]  = 0.0f;
        vS[k]  = 0.0f;
    }

    // Preload x for t = 0. Invalid lanes: -1e30 (finite; exp underflows to 0).
    {
        const float* xr = x + (size_t)b * D_SIZE;
        #pragma unroll
        for (int k = 0; k < NPT; ++k) {
            const int d = tid + k * BLOCK;
            xa[k] = (d < D_SIZE) ? xr[d] : -1e30f;
        }
    }

    for (int t = 0; t < T_STEPS; ++t) {
        // ---- row softmax entropy: H = logZ - W/Z ----
        float m_l = -1e30f;
        #pragma unroll
        for (int k = 0; k < NPT; ++k) m_l = fmaxf(m_l, xa[k]);
        const float m = blockReduceMax(m_l, sA);

        float Z = 0.0f, W = 0.0f;
        #pragma unroll
        for (int k = 0; k < NPT; ++k) {
            const float u = xa[k] - m;
            const float e = __expf(u);
            Z += e;
            W += e * u;
        }
        blockReduceSum2(Z, W, sA, sB);
        const float entropy = __logf(Z) - W / Z;   // +1e-8 term: <=2e-5 error

        // ---- compressed + global mean|c| partial ----
        float s_l = 0.0f;
        #pragma unroll
        for (int k = 0; k < NPT; ++k) {
            const float cm = sigmoidf_(acg[k] * entropy);
            const float c  = xa[k] * cm * gg[k];
            ca[k] = c;
            s_l += fabsf(c);
        }
        const float bs = blockReduceSum(s_l, sA);
        if (tid == 0) atomicAdd(&ws[ACC_STRIDE * t], bs);

        // ---- prefetch next x behind the barrier ----
        if (t + 1 < T_STEPS) {
            const float* xr = x + ((size_t)(t + 1) * B_SIZE + b) * D_SIZE;
            #pragma unroll
            for (int k = 0; k < NPT; ++k) {
                const int d = tid + k * BLOCK;
                xa[k] = (d < D_SIZE) ? xr[d] : -1e30f;
            }
        }

        grid_barrier(cnt, gen, t);

        const float total = __hip_atomic_load(&ws[ACC_STRIDE * t],
                                              __ATOMIC_ACQUIRE,
                                              __HIP_MEMORY_SCOPE_AGENT);
        const float binding = total * invBD;

        // ---- LIF update + spike store ----
        float* orow = out + ((size_t)t * B_SIZE + b) * D_SIZE;
        #pragma unroll
        for (int k = 0; k < NPT; ++k) {
            const float i2 = sd * iS[k] + ca[k] * binding;
            const float v2 = md * vS[k] + i2;
            const float sp = sigmoidf_(v2 - th);
            iS[k] = i2;
            vS[k] = v2 - sp * th;
            const int d = tid + k * BLOCK;
            if (d < D_SIZE) orow[d] = sp;
        }
    }
}

extern "C" void kernel_launch(void* const* d_in, const int* in_sizes, int n_in,
                              void* d_out, int out_size, void* d_ws, size_t ws_size,
                              hipStream_t stream) {
    const float* x   = (const float*)d_in[0];
    const float* ac  = (const float*)d_in[1];
    const float* tw  = (const float*)d_in[2];
    const float* ig  = (const float*)d_in[3];
    const float* mdp = (const float*)d_in[4];
    const float* sdp = (const float*)d_in[5];
    const float* thp = (const float*)d_in[6];
    float* out = (float*)d_out;
    float* ws  = (float*)d_ws;

    // ws is poisoned 0xAA before every timed call — re-zero accumulators+barrier.
    zero_ws_kernel<<<1, BLOCK, 0, stream>>>(ws);

    snn_atic_lif<<<GRID, BLOCK, 0, stream>>>(x, ac, tw, ig, mdp, sdp, thp, out, ws);
}

// Round 3
// 390.270 us; speedup vs baseline: 7.8459x; 7.8459x over previous
//
#include <hip/hip_runtime.h>

#define T_STEPS 20
#define B_SIZE  1024
#define D_SIZE  2312
#define BD      (B_SIZE * D_SIZE)          // 2,367,488
#define BLOCK   256
#define ROW_F4  (D_SIZE / 4)               // 578 float4 per row (exact)
#define F4_FULL 2                          // k=0,1 always valid; k=2 iff tid<66
#define K2_LIM  (ROW_F4 - 2 * BLOCK)       // 66

// ws layout (floats):
//   acc[t]  at ws[32*t], t<20 (padded 128B apart for atomic spread)
//   ent[t*B+b] at ws[1024 + t*1024 + b]  (20480 floats)
//   geff[d] at ws[21504 + d]             (2312 floats)
#define ACC_STRIDE 32
#define ENT_OFF    1024
#define GEFF_OFF   (ENT_OFF + T_STEPS * B_SIZE)   // 21504
#define WS_WORDS   (GEFF_OFF + D_SIZE)            // 23816 floats ~ 95 KB

__device__ __forceinline__ float sigmoidf_(float x) {
    return 1.0f / (1.0f + __expf(-x));
}

__device__ __forceinline__ float blockReduceMax(float v, float* s) {
    #pragma unroll
    for (int o = 32; o > 0; o >>= 1) v = fmaxf(v, __shfl_down(v, o, 64));
    const int wid = threadIdx.x >> 6;
    if ((threadIdx.x & 63) == 0) s[wid] = v;
    __syncthreads();
    float r = fmaxf(fmaxf(s[0], s[1]), fmaxf(s[2], s[3]));
    __syncthreads();
    return r;
}

__device__ __forceinline__ float blockReduceSum(float v, float* s) {
    #pragma unroll
    for (int o = 32; o > 0; o >>= 1) v += __shfl_down(v, o, 64);
    const int wid = threadIdx.x >> 6;
    if ((threadIdx.x & 63) == 0) s[wid] = v;
    __syncthreads();
    float r = (s[0] + s[1]) + (s[2] + s[3]);
    __syncthreads();
    return r;
}

__device__ __forceinline__ void blockReduceSum2(float& a, float& b, float* sa, float* sb) {
    #pragma unroll
    for (int o = 32; o > 0; o >>= 1) {
        a += __shfl_down(a, o, 64);
        b += __shfl_down(b, o, 64);
    }
    const int wid = threadIdx.x >> 6;
    if ((threadIdx.x & 63) == 0) { sa[wid] = a; sb[wid] = b; }
    __syncthreads();
    a = (sa[0] + sa[1]) + (sa[2] + sa[3]);
    b = (sb[0] + sb[1]) + (sb[2] + sb[3]);
    __syncthreads();
}

// Zero acc slots + precompute geff[d] = sigmoid(tw[d])*sigmoid(ig[d]).
__global__ void prep_kernel(const float* __restrict__ tw, const float* __restrict__ ig,
                            float* __restrict__ ws) {
    const int i = blockIdx.x * BLOCK + threadIdx.x;
    if (i < T_STEPS * ACC_STRIDE) ws[i] = 0.0f;
    if (i < D_SIZE) ws[GEFF_OFF + i] = sigmoidf_(tw[i]) * sigmoidf_(ig[i]);
}

// One block per (t,b) row: softmax entropy + sum|compressed| -> acc[t], ent[t,b].
// Row x held in 3 float4 registers per thread (12 floats) — no spill surface.
__global__ void __launch_bounds__(BLOCK)
phase1_entropy(const float* __restrict__ x, const float* __restrict__ ac,
               float* __restrict__ ws) {
    __shared__ float sA[4];
    __shared__ float sB[4];

    const int tb  = blockIdx.x;        // t*B_SIZE + b
    const int t   = tb >> 10;          // B_SIZE = 1024
    const int tid = threadIdx.x;
    const bool tail_ok = (tid < K2_LIM);

    const float4* xr = (const float4*)(x + (size_t)tb * D_SIZE);
    float4 xv[3];
    float m_l = -1e30f;
    #pragma unroll
    for (int k = 0; k < 3; ++k) {
        const bool ok = (k < F4_FULL) || tail_ok;
        xv[k] = ok ? xr[tid + k * BLOCK]
                   : make_float4(-1e30f, -1e30f, -1e30f, -1e30f);
        m_l = fmaxf(fmaxf(m_l, fmaxf(xv[k].x, xv[k].y)),
                    fmaxf(xv[k].z, xv[k].w));
    }
    const float m = blockReduceMax(m_l, sA);

    float Z = 0.0f, W = 0.0f;
    #pragma unroll
    for (int k = 0; k < 3; ++k) {
        const float u0 = xv[k].x - m, u1 = xv[k].y - m;
        const float u2 = xv[k].z - m, u3 = xv[k].w - m;
        const float e0 = __expf(u0), e1 = __expf(u1);
        const float e2 = __expf(u2), e3 = __expf(u3);
        Z += (e0 + e1) + (e2 + e3);
        W += (e0 * u0 + e1 * u1) + (e2 * u2 + e3 * u3);   // exp(-huge)=0 kills tail
    }
    blockReduceSum2(Z, W, sA, sB);
    const float H = __logf(Z) - W / Z;   // ref's +1e-8 inside log: <=2e-5 error

    const float4* ac4 = (const float4*)ac;
    const float4* g4  = (const float4*)(ws + GEFF_OFF);
    float s_l = 0.0f;
    #pragma unroll
    for (int k = 0; k < 3; ++k) {
        const bool ok = (k < F4_FULL) || tail_ok;
        if (ok) {
            const int f = tid + k * BLOCK;
            const float4 a = ac4[f];
            const float4 g = g4[f];
            s_l += fabsf(xv[k].x * sigmoidf_(a.x * H) * g.x)
                 + fabsf(xv[k].y * sigmoidf_(a.y * H) * g.y)
                 + fabsf(xv[k].z * sigmoidf_(a.z * H) * g.z)
                 + fabsf(xv[k].w * sigmoidf_(a.w * H) * g.w);
        }
    }
    const float bs = blockReduceSum(s_l, sA);
    if (tid == 0) {
        atomicAdd(&ws[ACC_STRIDE * t], bs);
        ws[ENT_OFF + tb] = H;
    }
}

// One float4 element-group per thread; LIF recurrence over t in registers.
__global__ void __launch_bounds__(BLOCK)
phase2_lif(const float* __restrict__ x, const float* __restrict__ ac,
           const float* __restrict__ ws,
           const float* __restrict__ mdp, const float* __restrict__ sdp,
           const float* __restrict__ thp, float* __restrict__ out) {
    const int idx = blockIdx.x * BLOCK + threadIdx.x;   // float4 index
    const int e0  = idx * 4;
    const int b   = e0 / D_SIZE;             // D_SIZE % 4 == 0 -> no row straddle
    const int d0  = e0 - b * D_SIZE;

    const float md = mdp[0];
    const float sd = sdp[0];
    const float th = thp[0];
    const float invBD = 1.0f / (float)BD;

    const float4 a = *(const float4*)(ac + d0);
    const float4 g = *(const float4*)(ws + GEFF_OFF + d0);

    float i0 = 0.f, i1 = 0.f, i2 = 0.f, i3 = 0.f;
    float v0 = 0.f, v1 = 0.f, v2 = 0.f, v3 = 0.f;

    for (int t = 0; t < T_STEPS; ++t) {
        const float4 xv = *(const float4*)(x + (size_t)t * BD + e0);
        const float H  = ws[ENT_OFF + t * B_SIZE + b];
        const float bs = ws[ACC_STRIDE * t] * invBD;

        const float c0 = xv.x * sigmoidf_(a.x * H) * g.x * bs;
        const float c1 = xv.y * sigmoidf_(a.y * H) * g.y * bs;
        const float c2 = xv.z * sigmoidf_(a.z * H) * g.z * bs;
        const float c3 = xv.w * sigmoidf_(a.w * H) * g.w * bs;

        i0 = sd * i0 + c0;  v0 = md * v0 + i0;
        i1 = sd * i1 + c1;  v1 = md * v1 + i1;
        i2 = sd * i2 + c2;  v2 = md * v2 + i2;
        i3 = sd * i3 + c3;  v3 = md * v3 + i3;

        const float s0 = sigmoidf_(v0 - th);
        const float s1 = sigmoidf_(v1 - th);
        const float s2 = sigmoidf_(v2 - th);
        const float s3 = sigmoidf_(v3 - th);
        v0 -= s0 * th;  v1 -= s1 * th;  v2 -= s2 * th;  v3 -= s3 * th;

        *(float4*)(out + (size_t)t * BD + e0) = make_float4(s0, s1, s2, s3);
    }
}

extern "C" void kernel_launch(void* const* d_in, const int* in_sizes, int n_in,
                              void* d_out, int out_size, void* d_ws, size_t ws_size,
                              hipStream_t stream) {
    const float* x   = (const float*)d_in[0];
    const float* ac  = (const float*)d_in[1];
    const float* tw  = (const float*)d_in[2];
    const float* ig  = (const float*)d_in[3];
    const float* mdp = (const float*)d_in[4];
    const float* sdp = (const float*)d_in[5];
    const float* thp = (const float*)d_in[6];
    float* out = (float*)d_out;
    float* ws  = (float*)d_ws;

    // ws poisoned 0xAA each timed call — prep rewrites everything phase1/2 read.
    prep_kernel<<<10, BLOCK, 0, stream>>>(tw, ig, ws);

    phase1_entropy<<<T_STEPS * B_SIZE, BLOCK, 0, stream>>>(x, ac, ws);

    phase2_lif<<<BD / 4 / BLOCK, BLOCK, 0, stream>>>(x, ac, ws, mdp, sdp, thp, out);
}